// Round 1
// baseline (346.587 us; speedup 1.0000x reference)
//
#include <hip/hip_runtime.h>

#define N_NODES 40000
#define N_EDGES 640000
#define NFEAT   128
#define H1      128   // 2*NHID
#define H2      64    // NHID

// ---- workspace layout (byte offsets, all 256-aligned) ----
#define OFF_SUP1   0UL          // 40000*128 f32 = 20,480,000
#define OFF_H      20480000UL   // 40000*128 f32 = 20,480,000
#define OFF_SUP2   40960000UL   // 40000*64  f32 = 10,240,000
#define OFF_ROWPTR 51200000UL   // 40001 i32 -> 160,256 (padded)
#define OFF_CURSOR 51360256UL   // 40000 i32 -> 160,000
#define OFF_CNT    51520256UL   // 40000 i32 -> 160,000
#define OFF_CSRC   51680256UL   // 640000 i32 -> 2,560,000
#define OFF_CSRW   54240256UL   // 640000 f32 -> 2,560,000
// total 56,800,256 bytes

__device__ __forceinline__ float comp4(const float4& v, int j) {
    return j == 0 ? v.x : j == 1 ? v.y : j == 2 ? v.z : v.w;
}

// support1 = x @ W1   (M=40000, K=128, N=128)
__global__ __launch_bounds__(256) void gemm1_k(const float* __restrict__ x,
                                               const float* __restrict__ W,
                                               float* __restrict__ out) {
    __shared__ float Ws[128 * 128];
    const int t = threadIdx.x;
#pragma unroll
    for (int i = 0; i < 16; ++i)
        ((float4*)Ws)[i * 256 + t] = ((const float4*)W)[i * 256 + t];
    __syncthreads();

    const int wave = t >> 6, lane = t & 63;
    const int rowBase = blockIdx.x * 64 + wave * 16;

    for (int it = 0; it < 4; ++it) {
        const int r0 = rowBase + it * 4;
        float acc[4][2] = {};
#pragma unroll 4
        for (int k4 = 0; k4 < 32; ++k4) {
            float4 xv[4];
#pragma unroll
            for (int i = 0; i < 4; ++i)
                xv[i] = *(const float4*)(x + (size_t)(r0 + i) * 128 + k4 * 4);
#pragma unroll
            for (int j = 0; j < 4; ++j) {
                const int k = k4 * 4 + j;
                const float w0 = Ws[k * 128 + lane];
                const float w1 = Ws[k * 128 + 64 + lane];
#pragma unroll
                for (int i = 0; i < 4; ++i) {
                    const float xs = comp4(xv[i], j);
                    acc[i][0] = fmaf(xs, w0, acc[i][0]);
                    acc[i][1] = fmaf(xs, w1, acc[i][1]);
                }
            }
        }
#pragma unroll
        for (int i = 0; i < 4; ++i) {
            out[(size_t)(r0 + i) * 128 + lane]      = acc[i][0];
            out[(size_t)(r0 + i) * 128 + 64 + lane] = acc[i][1];
        }
    }
}

// support2 = h @ W2   (M=40000, K=128, N=64)
__global__ __launch_bounds__(256) void gemm2_k(const float* __restrict__ h,
                                               const float* __restrict__ W,
                                               float* __restrict__ out) {
    __shared__ float Ws[128 * 64];
    const int t = threadIdx.x;
#pragma unroll
    for (int i = 0; i < 8; ++i)
        ((float4*)Ws)[i * 256 + t] = ((const float4*)W)[i * 256 + t];
    __syncthreads();

    const int wave = t >> 6, lane = t & 63;

    for (int it = 0; it < 2; ++it) {
        const int r0 = blockIdx.x * 64 + it * 32 + wave * 8;
        float acc[8] = {};
#pragma unroll 2
        for (int k4 = 0; k4 < 32; ++k4) {
            float4 xv[8];
#pragma unroll
            for (int i = 0; i < 8; ++i)
                xv[i] = *(const float4*)(h + (size_t)(r0 + i) * 128 + k4 * 4);
#pragma unroll
            for (int j = 0; j < 4; ++j) {
                const float wv = Ws[(k4 * 4 + j) * 64 + lane];
#pragma unroll
                for (int i = 0; i < 8; ++i)
                    acc[i] = fmaf(comp4(xv[i], j), wv, acc[i]);
            }
        }
#pragma unroll
        for (int i = 0; i < 8; ++i)
            out[(size_t)(r0 + i) * 64 + lane] = acc[i];
    }
}

__global__ void zero_k(int* __restrict__ cnt) {
    int i = blockIdx.x * blockDim.x + threadIdx.x;
    if (i < N_NODES) cnt[i] = 0;
}

__global__ void hist_k(const int* __restrict__ edst, int* __restrict__ cnt) {
    int i = blockIdx.x * blockDim.x + threadIdx.x;
    if (i < N_EDGES) atomicAdd(&cnt[edst[i]], 1);
}

// single-block inclusive scan over counts -> row_ptr (exclusive) + cursor copy
__global__ __launch_bounds__(1024) void scan_k(const int* __restrict__ cnt,
                                               int* __restrict__ row_ptr,
                                               int* __restrict__ cursor) {
    __shared__ int wsum[16];
    const int t = threadIdx.x;
    const int lane = t & 63, wv = t >> 6;
    int offset = 0;
    if (t == 0) row_ptr[0] = 0;

    for (int base = 0; base < N_NODES; base += 1024) {
        const int idx = base + t;
        const int v = (idx < N_NODES) ? cnt[idx] : 0;
        int incl = v;
#pragma unroll
        for (int d = 1; d < 64; d <<= 1) {
            int o = __shfl_up(incl, d);
            if (lane >= d) incl += o;
        }
        if (lane == 63) wsum[wv] = incl;
        __syncthreads();
        if (t < 16) {
            int s = wsum[t];
#pragma unroll
            for (int d = 1; d < 16; d <<= 1) {
                int o = __shfl_up(s, d);
                if (t >= d) s += o;
            }
            wsum[t] = s;
        }
        __syncthreads();
        const int woff = (wv > 0) ? wsum[wv - 1] : 0;
        incl += woff;
        const int total = wsum[15];
        if (idx < N_NODES) {
            row_ptr[idx + 1] = offset + incl;
            cursor[idx]      = offset + incl - v;
        }
        offset += total;
        __syncthreads();
    }
}

__global__ void scatter_k(const int* __restrict__ esrc, const int* __restrict__ edst,
                          const float* __restrict__ ew, int* __restrict__ cursor,
                          int* __restrict__ csrc, float* __restrict__ csrw) {
    int i = blockIdx.x * blockDim.x + threadIdx.x;
    if (i < N_EDGES) {
        int pos = atomicAdd(&cursor[edst[i]], 1);
        csrc[pos] = esrc[i];
        csrw[pos] = ew[i];
    }
}

// h = relu( spmm(adj, support1) + b1 ),  D=128, one wave per node
__global__ __launch_bounds__(256) void spmm1_k(const float* __restrict__ sup,
                                               const int* __restrict__ row_ptr,
                                               const int* __restrict__ csrc,
                                               const float* __restrict__ csrw,
                                               const float* __restrict__ b,
                                               float* __restrict__ h) {
    const int wid = blockIdx.x * 4 + (threadIdx.x >> 6);
    const int lane = threadIdx.x & 63;
    if (wid >= N_NODES) return;
    const int e0 = row_ptr[wid], e1 = row_ptr[wid + 1];
    float a0 = 0.f, a1 = 0.f;
    for (int e = e0; e < e1; ++e) {
        const int s = csrc[e];
        const float w = csrw[e];
        const float* row = sup + (size_t)s * 128;
        a0 = fmaf(w, row[lane], a0);
        a1 = fmaf(w, row[64 + lane], a1);
    }
    const float r0 = a0 + b[lane];
    const float r1 = a1 + b[64 + lane];
    h[(size_t)wid * 128 + lane]      = fmaxf(r0, 0.f);
    h[(size_t)wid * 128 + 64 + lane] = fmaxf(r1, 0.f);
}

// out = spmm(adj, support2) + b2,  D=64, one wave per node
__global__ __launch_bounds__(256) void spmm2_k(const float* __restrict__ sup,
                                               const int* __restrict__ row_ptr,
                                               const int* __restrict__ csrc,
                                               const float* __restrict__ csrw,
                                               const float* __restrict__ b,
                                               float* __restrict__ out) {
    const int wid = blockIdx.x * 4 + (threadIdx.x >> 6);
    const int lane = threadIdx.x & 63;
    if (wid >= N_NODES) return;
    const int e0 = row_ptr[wid], e1 = row_ptr[wid + 1];
    float a0 = 0.f;
    for (int e = e0; e < e1; ++e) {
        const int s = csrc[e];
        const float w = csrw[e];
        a0 = fmaf(w, sup[(size_t)s * 64 + lane], a0);
    }
    out[(size_t)wid * 64 + lane] = a0 + b[lane];
}

extern "C" void kernel_launch(void* const* d_in, const int* in_sizes, int n_in,
                              void* d_out, int out_size, void* d_ws, size_t ws_size,
                              hipStream_t stream) {
    const float* x    = (const float*)d_in[0];
    const int*   esrc = (const int*)d_in[1];
    const int*   edst = (const int*)d_in[2];
    const float* ew   = (const float*)d_in[3];
    const float* W1   = (const float*)d_in[4];
    const float* b1   = (const float*)d_in[5];
    const float* W2   = (const float*)d_in[6];
    const float* b2   = (const float*)d_in[7];
    float* out = (float*)d_out;

    char* ws = (char*)d_ws;
    float* sup1    = (float*)(ws + OFF_SUP1);
    float* h       = (float*)(ws + OFF_H);
    float* sup2    = (float*)(ws + OFF_SUP2);
    int*   row_ptr = (int*)(ws + OFF_ROWPTR);
    int*   cursor  = (int*)(ws + OFF_CURSOR);
    int*   cnt     = (int*)(ws + OFF_CNT);
    int*   csrc    = (int*)(ws + OFF_CSRC);
    float* csrw    = (float*)(ws + OFF_CSRW);

    // CSR build
    zero_k<<<(N_NODES + 255) / 256, 256, 0, stream>>>(cnt);
    hist_k<<<(N_EDGES + 255) / 256, 256, 0, stream>>>(edst, cnt);
    scan_k<<<1, 1024, 0, stream>>>(cnt, row_ptr, cursor);
    scatter_k<<<(N_EDGES + 255) / 256, 256, 0, stream>>>(esrc, edst, ew, cursor, csrc, csrw);

    // layer 1
    gemm1_k<<<625, 256, 0, stream>>>(x, W1, sup1);
    spmm1_k<<<10000, 256, 0, stream>>>(sup1, row_ptr, csrc, csrw, b1, h);

    // layer 2
    gemm2_k<<<625, 256, 0, stream>>>(h, W2, sup2);
    spmm2_k<<<10000, 256, 0, stream>>>(sup2, row_ptr, csrc, csrw, b2, out);
}

// Round 2
// 223.671 us; speedup vs baseline: 1.5495x; 1.5495x over previous
//
#include <hip/hip_runtime.h>

#define N_NODES 40000
#define N_EDGES 640000
#define NFEAT   128
#define H1      128   // 2*NHID
#define H2      64    // NHID
#define NBLK    40    // ceil(40000/1024)

// ---- workspace layout (byte offsets, all 256-aligned) ----
#define OFF_SUP1   0UL          // 40000*128 bf16 = 10,240,000
#define OFF_H      10240000UL   // 40000*128 bf16 = 10,240,000
#define OFF_SUP2   20480000UL   // 40000*64  bf16 =  5,120,000
#define OFF_ROWPTR 25600000UL   // 40001 i32 -> 160,256 (padded)
#define OFF_CURSOR 25760256UL   // 40000 i32 -> 160,000
#define OFF_CNT    25920256UL   // 40000 i32 -> 160,000
#define OFF_BLKSUM 26080256UL   // 40 i32 -> 256
#define OFF_CSRC   26080512UL   // 640000 i32 -> 2,560,000
#define OFF_CSRW   28640512UL   // 640000 f32 -> 2,560,000
// total 31,200,512 bytes

typedef unsigned int uint;
typedef unsigned short ushort;

__device__ __forceinline__ float comp4(const float4& v, int j) {
    return j == 0 ? v.x : j == 1 ? v.y : j == 2 ? v.z : v.w;
}
// bf16 helpers (bit-level, round-to-nearest-even on pack)
__device__ __forceinline__ float bl(uint u) { union { uint i; float f; } c; c.i = u << 16; return c.f; }
__device__ __forceinline__ float bh(uint u) { union { uint i; float f; } c; c.i = u & 0xFFFF0000u; return c.f; }
__device__ __forceinline__ float bfu(ushort u) { union { uint i; float f; } c; c.i = ((uint)u) << 16; return c.f; }
__device__ __forceinline__ ushort f2b(float f) {
    union { float f; uint i; } c; c.f = f;
    uint u = c.i + 0x7FFFu + ((c.i >> 16) & 1u);
    return (ushort)(u >> 16);
}

// support1 = x @ W1  (M=40000, K=128, N=128), f32 compute, bf16 out
__global__ __launch_bounds__(256) void gemm1_k(const float* __restrict__ x,
                                               const float* __restrict__ W,
                                               ushort* __restrict__ out) {
    __shared__ float Ws[128 * 128];
    const int t = threadIdx.x;
#pragma unroll
    for (int i = 0; i < 16; ++i)
        ((float4*)Ws)[i * 256 + t] = ((const float4*)W)[i * 256 + t];
    __syncthreads();

    const int wave = t >> 6, lane = t & 63;
    const int rowBase = blockIdx.x * 64 + wave * 16;
    const float2* __restrict__ Ws2 = (const float2*)Ws;  // Ws2[k*64 + lane] = cols {2l,2l+1}

    for (int it = 0; it < 4; ++it) {
        const int r0 = rowBase + it * 4;
        float acc0[4] = {}, acc1[4] = {};
#pragma unroll 4
        for (int k4 = 0; k4 < 32; ++k4) {
            float4 xv[4];
#pragma unroll
            for (int i = 0; i < 4; ++i)
                xv[i] = *(const float4*)(x + (size_t)(r0 + i) * 128 + k4 * 4);
#pragma unroll
            for (int j = 0; j < 4; ++j) {
                const float2 w = Ws2[(k4 * 4 + j) * 64 + lane];
#pragma unroll
                for (int i = 0; i < 4; ++i) {
                    const float xs = comp4(xv[i], j);
                    acc0[i] = fmaf(xs, w.x, acc0[i]);
                    acc1[i] = fmaf(xs, w.y, acc1[i]);
                }
            }
        }
#pragma unroll
        for (int i = 0; i < 4; ++i) {
            const uint p = (uint)f2b(acc0[i]) | ((uint)f2b(acc1[i]) << 16);
            ((uint*)out)[(size_t)(r0 + i) * 64 + lane] = p;
        }
    }
}

// support2 = h @ W2  (M=40000, K=128, N=64), bf16 in, f32 compute, bf16 out
__global__ __launch_bounds__(256) void gemm2_k(const ushort* __restrict__ h,
                                               const float* __restrict__ W,
                                               ushort* __restrict__ out) {
    __shared__ float Ws[128 * 64];
    const int t = threadIdx.x;
#pragma unroll
    for (int i = 0; i < 8; ++i)
        ((float4*)Ws)[i * 256 + t] = ((const float4*)W)[i * 256 + t];
    __syncthreads();

    const int wave = t >> 6, lane = t & 63;

    for (int it = 0; it < 2; ++it) {
        const int r0 = blockIdx.x * 64 + it * 32 + wave * 8;
        float acc[8] = {};
#pragma unroll 2
        for (int k8 = 0; k8 < 16; ++k8) {
            uint4 hv[8];
#pragma unroll
            for (int i = 0; i < 8; ++i)
                hv[i] = ((const uint4*)(h + (size_t)(r0 + i) * 128))[k8];
#pragma unroll
            for (int j2 = 0; j2 < 4; ++j2) {
                const float wlo = Ws[(k8 * 8 + j2 * 2) * 64 + lane];
                const float whi = Ws[(k8 * 8 + j2 * 2 + 1) * 64 + lane];
#pragma unroll
                for (int i = 0; i < 8; ++i) {
                    const uint u = j2 == 0 ? hv[i].x : j2 == 1 ? hv[i].y : j2 == 2 ? hv[i].z : hv[i].w;
                    acc[i] = fmaf(bl(u), wlo, acc[i]);
                    acc[i] = fmaf(bh(u), whi, acc[i]);
                }
            }
        }
#pragma unroll
        for (int i = 0; i < 8; ++i)
            out[(size_t)(r0 + i) * 64 + lane] = f2b(acc[i]);
    }
}

__global__ void zero_k(int* __restrict__ cnt) {
    int i = blockIdx.x * blockDim.x + threadIdx.x;
    if (i < N_NODES) cnt[i] = 0;
}

__global__ void hist_k(const int* __restrict__ edst, int* __restrict__ cnt) {
    int i = blockIdx.x * blockDim.x + threadIdx.x;
    if (i < N_EDGES) atomicAdd(&cnt[edst[i]], 1);
}

// ---- hierarchical scan: reduce per 1024-block -> scan 40 sums -> offset scan ----
__global__ __launch_bounds__(1024) void reduce_k(const int* __restrict__ cnt,
                                                 int* __restrict__ blksum) {
    __shared__ int ws[16];
    const int t = threadIdx.x;
    const int idx = blockIdx.x * 1024 + t;
    int v = (idx < N_NODES) ? cnt[idx] : 0;
#pragma unroll
    for (int d = 1; d < 64; d <<= 1) v += __shfl_xor(v, d);
    if ((t & 63) == 0) ws[t >> 6] = v;
    __syncthreads();
    if (t < 16) {
        int s = ws[t];
#pragma unroll
        for (int d = 1; d < 16; d <<= 1) s += __shfl_xor(s, d);
        if (t == 0) blksum[blockIdx.x] = s;
    }
}

__global__ void scanblk_k(int* __restrict__ blksum) {  // 1 block, 64 threads, inclusive
    const int t = threadIdx.x;
    int v = (t < NBLK) ? blksum[t] : 0;
#pragma unroll
    for (int d = 1; d < 64; d <<= 1) {
        int o = __shfl_up(v, d);
        if (t >= d) v += o;
    }
    if (t < NBLK) blksum[t] = v;
}

__global__ __launch_bounds__(1024) void scan3_k(const int* __restrict__ cnt,
                                                const int* __restrict__ blksum,
                                                int* __restrict__ row_ptr,
                                                int* __restrict__ cursor) {
    __shared__ int wsum[16];
    const int t = threadIdx.x, lane = t & 63, wv = t >> 6;
    const int idx = blockIdx.x * 1024 + t;
    const int v = (idx < N_NODES) ? cnt[idx] : 0;
    int incl = v;
#pragma unroll
    for (int d = 1; d < 64; d <<= 1) {
        int o = __shfl_up(incl, d);
        if (lane >= d) incl += o;
    }
    if (lane == 63) wsum[wv] = incl;
    __syncthreads();
    if (t < 16) {
        int s = wsum[t];
#pragma unroll
        for (int d = 1; d < 16; d <<= 1) {
            int o = __shfl_up(s, d);
            if (t >= d) s += o;
        }
        wsum[t] = s;
    }
    __syncthreads();
    const int base = (blockIdx.x ? blksum[blockIdx.x - 1] : 0) + (wv ? wsum[wv - 1] : 0);
    if (idx < N_NODES) {
        row_ptr[idx + 1] = base + incl;
        cursor[idx]      = base + incl - v;
    }
    if (idx == 0) row_ptr[0] = 0;
}

__global__ void scatter_k(const int* __restrict__ esrc, const int* __restrict__ edst,
                          const float* __restrict__ ew, int* __restrict__ cursor,
                          int* __restrict__ csrc, float* __restrict__ csrw) {
    int i = blockIdx.x * blockDim.x + threadIdx.x;
    if (i < N_EDGES) {
        int pos = atomicAdd(&cursor[edst[i]], 1);
        csrc[pos] = esrc[i];
        csrw[pos] = ew[i];
    }
}

// h = relu( spmm(adj, sup1) + b1 ),  D=128 bf16 in, bf16 out. One wave/node,
// lane covers features {2l, 2l+1}; 4-deep edge unroll -> 4 gathers in flight.
__global__ __launch_bounds__(256) void spmm1_k(const ushort* __restrict__ sup,
                                               const int* __restrict__ rp,
                                               const int* __restrict__ csrc,
                                               const float* __restrict__ csrw,
                                               const float* __restrict__ b,
                                               ushort* __restrict__ h) {
    const int wid = blockIdx.x * 4 + (threadIdx.x >> 6);
    const int lane = threadIdx.x & 63;
    const int e0 = rp[wid], e1 = rp[wid + 1];
    float a0 = 0.f, a1 = 0.f, a2 = 0.f, a3 = 0.f;
    int e = e0;
    for (; e + 4 <= e1; e += 4) {
        const int s0 = csrc[e], s1 = csrc[e + 1], s2 = csrc[e + 2], s3 = csrc[e + 3];
        const float w0 = csrw[e], w1 = csrw[e + 1], w2 = csrw[e + 2], w3 = csrw[e + 3];
        const uint v0 = ((const uint*)(sup + ((size_t)s0 << 7)))[lane];
        const uint v1 = ((const uint*)(sup + ((size_t)s1 << 7)))[lane];
        const uint v2 = ((const uint*)(sup + ((size_t)s2 << 7)))[lane];
        const uint v3 = ((const uint*)(sup + ((size_t)s3 << 7)))[lane];
        a0 = fmaf(w0, bl(v0), a0); a1 = fmaf(w0, bh(v0), a1);
        a2 = fmaf(w1, bl(v1), a2); a3 = fmaf(w1, bh(v1), a3);
        a0 = fmaf(w2, bl(v2), a0); a1 = fmaf(w2, bh(v2), a1);
        a2 = fmaf(w3, bl(v3), a2); a3 = fmaf(w3, bh(v3), a3);
    }
    for (; e < e1; ++e) {
        const int s = csrc[e];
        const float w = csrw[e];
        const uint v = ((const uint*)(sup + ((size_t)s << 7)))[lane];
        a0 = fmaf(w, bl(v), a0); a1 = fmaf(w, bh(v), a1);
    }
    a0 += a2; a1 += a3;
    const float2 bb = ((const float2*)b)[lane];
    a0 = fmaxf(a0 + bb.x, 0.f);
    a1 = fmaxf(a1 + bb.y, 0.f);
    ((uint*)h)[(size_t)wid * 64 + lane] = (uint)f2b(a0) | ((uint)f2b(a1) << 16);
}

// out = spmm(adj, sup2) + b2,  D=64 bf16 in, f32 out. One wave/node.
__global__ __launch_bounds__(256) void spmm2_k(const ushort* __restrict__ sup,
                                               const int* __restrict__ rp,
                                               const int* __restrict__ csrc,
                                               const float* __restrict__ csrw,
                                               const float* __restrict__ b,
                                               float* __restrict__ out) {
    const int wid = blockIdx.x * 4 + (threadIdx.x >> 6);
    const int lane = threadIdx.x & 63;
    const int e0 = rp[wid], e1 = rp[wid + 1];
    float a0 = 0.f, a1 = 0.f, a2 = 0.f, a3 = 0.f;
    int e = e0;
    for (; e + 4 <= e1; e += 4) {
        const int s0 = csrc[e], s1 = csrc[e + 1], s2 = csrc[e + 2], s3 = csrc[e + 3];
        const float w0 = csrw[e], w1 = csrw[e + 1], w2 = csrw[e + 2], w3 = csrw[e + 3];
        const float v0 = bfu(sup[((size_t)s0 << 6) + lane]);
        const float v1 = bfu(sup[((size_t)s1 << 6) + lane]);
        const float v2 = bfu(sup[((size_t)s2 << 6) + lane]);
        const float v3 = bfu(sup[((size_t)s3 << 6) + lane]);
        a0 = fmaf(w0, v0, a0);
        a1 = fmaf(w1, v1, a1);
        a2 = fmaf(w2, v2, a2);
        a3 = fmaf(w3, v3, a3);
    }
    for (; e < e1; ++e) {
        a0 = fmaf(csrw[e], bfu(sup[((size_t)csrc[e] << 6) + lane]), a0);
    }
    out[(size_t)wid * 64 + lane] = (a0 + a1) + (a2 + a3) + b[lane];
}

extern "C" void kernel_launch(void* const* d_in, const int* in_sizes, int n_in,
                              void* d_out, int out_size, void* d_ws, size_t ws_size,
                              hipStream_t stream) {
    const float* x    = (const float*)d_in[0];
    const int*   esrc = (const int*)d_in[1];
    const int*   edst = (const int*)d_in[2];
    const float* ew   = (const float*)d_in[3];
    const float* W1   = (const float*)d_in[4];
    const float* b1   = (const float*)d_in[5];
    const float* W2   = (const float*)d_in[6];
    const float* b2   = (const float*)d_in[7];
    float* out = (float*)d_out;

    char* ws = (char*)d_ws;
    ushort* sup1   = (ushort*)(ws + OFF_SUP1);
    ushort* h      = (ushort*)(ws + OFF_H);
    ushort* sup2   = (ushort*)(ws + OFF_SUP2);
    int*   row_ptr = (int*)(ws + OFF_ROWPTR);
    int*   cursor  = (int*)(ws + OFF_CURSOR);
    int*   cnt     = (int*)(ws + OFF_CNT);
    int*   blksum  = (int*)(ws + OFF_BLKSUM);
    int*   csrc    = (int*)(ws + OFF_CSRC);
    float* csrw    = (float*)(ws + OFF_CSRW);

    // CSR build
    zero_k<<<(N_NODES + 255) / 256, 256, 0, stream>>>(cnt);
    hist_k<<<(N_EDGES + 255) / 256, 256, 0, stream>>>(edst, cnt);
    reduce_k<<<NBLK, 1024, 0, stream>>>(cnt, blksum);
    scanblk_k<<<1, 64, 0, stream>>>(blksum);
    scan3_k<<<NBLK, 1024, 0, stream>>>(cnt, blksum, row_ptr, cursor);
    scatter_k<<<(N_EDGES + 255) / 256, 256, 0, stream>>>(esrc, edst, ew, cursor, csrc, csrw);

    // layer 1
    gemm1_k<<<625, 256, 0, stream>>>(x, W1, sup1);
    spmm1_k<<<10000, 256, 0, stream>>>(sup1, row_ptr, csrc, csrw, b1, h);

    // layer 2
    gemm2_k<<<625, 256, 0, stream>>>(h, W2, sup2);
    spmm2_k<<<10000, 256, 0, stream>>>(sup2, row_ptr, csrc, csrw, b2, out);
}

// Round 3
// 169.101 us; speedup vs baseline: 2.0496x; 1.3227x over previous
//
#include <hip/hip_runtime.h>

#define N_NODES 40000
#define N_EDGES 640000
#define NFEAT   128
#define H1      128   // 2*NHID
#define H2      64    // NHID
#define NBLK    40    // ceil(40000/1024)

// ---- workspace layout (byte offsets, all 256-aligned) ----
#define OFF_SUP1   0UL          // 40000*128 bf16 = 10,240,000
#define OFF_H      10240000UL   // 40000*128 bf16 = 10,240,000
#define OFF_SUP2   20480000UL   // 40000*64  bf16 =  5,120,000
#define OFF_ROWPTR 25600000UL   // 40001 i32 -> 160,256 (padded)
#define OFF_CURSOR 25760256UL   // 40000 i32 -> 160,000
#define OFF_CNT    25920256UL   // 40000 i32 -> 160,000
#define OFF_BLKSUM 26080256UL   // 40 i32 -> 256
#define OFF_CSRC   26080512UL   // 640000 i32 -> 2,560,000
#define OFF_CSRW   28640512UL   // 640000 f32 -> 2,560,000
#define OFF_W1T    31200512UL   // 128*128 bf16 -> 32,768
#define OFF_W2T    31233280UL   // 64*128 bf16 -> 16,384
// total 31,249,664 bytes

typedef unsigned int uint;
typedef unsigned short ushort;
typedef __attribute__((ext_vector_type(8))) short bf16x8;
typedef __attribute__((ext_vector_type(4))) float f32x4;

// bf16 helpers (bit-level, round-to-nearest-even on pack)
__device__ __forceinline__ float bl(uint u) { union { uint i; float f; } c; c.i = u << 16; return c.f; }
__device__ __forceinline__ float bh(uint u) { union { uint i; float f; } c; c.i = u & 0xFFFF0000u; return c.f; }
__device__ __forceinline__ float bfu(ushort u) { union { uint i; float f; } c; c.i = ((uint)u) << 16; return c.f; }
__device__ __forceinline__ ushort f2b(float f) {
    union { float f; uint i; } c; c.f = f;
    uint u = c.i + 0x7FFFu + ((c.i >> 16) & 1u);
    return (ushort)(u >> 16);
}

// W1 [128][128] f32 -> W1T [n][k] bf16 ; W2 [128][64] f32 -> W2T [n][k] bf16
__global__ void wtrans_k(const float* __restrict__ W1, const float* __restrict__ W2,
                         ushort* __restrict__ W1T, ushort* __restrict__ W2T) {
    const int i = blockIdx.x * 256 + threadIdx.x;
    if (i < 128 * 128) {
        const int c = i >> 7, k = i & 127;
        W1T[i] = f2b(W1[k * 128 + c]);
    }
    if (i < 64 * 128) {
        const int c = i >> 7, k = i & 127;
        W2T[i] = f2b(W2[k * 64 + c]);
    }
}

// sup1 = x @ W1  (M=40000, K=128, N=128) — MFMA bf16, fp32-in cvt inline.
// wave = 16 rows; A: row=lane&15, k=(lane>>4)*8+i; B from WT rows (contiguous);
// C/D: col=lane&15, row=(lane>>4)*4+reg.
__global__ __launch_bounds__(256) void gemm1_k(const float* __restrict__ x,
                                               const ushort* __restrict__ WT,
                                               ushort* __restrict__ out) {
    const int lane = threadIdx.x & 63;
    const int m0 = blockIdx.x * 64 + (threadIdx.x >> 6) * 16;
    const int r = lane & 15, kg = lane >> 4;

    bf16x8 a[4];
    const float* xp = x + (size_t)(m0 + r) * 128 + kg * 8;
#pragma unroll
    for (int kt = 0; kt < 4; ++kt) {
        float xf[8];
        *(float4*)(xf)     = *(const float4*)(xp + kt * 32);
        *(float4*)(xf + 4) = *(const float4*)(xp + kt * 32 + 4);
        bf16x8 v;
#pragma unroll
        for (int i = 0; i < 8; ++i) v[i] = (short)f2b(xf[i]);
        a[kt] = v;
    }

#pragma unroll
    for (int nt = 0; nt < 8; ++nt) {
        const ushort* wp = WT + (size_t)(nt * 16 + r) * 128 + kg * 8;
        f32x4 acc = {0.f, 0.f, 0.f, 0.f};
#pragma unroll
        for (int kt = 0; kt < 4; ++kt) {
            const bf16x8 bfr = *(const bf16x8*)(wp + kt * 32);
            acc = __builtin_amdgcn_mfma_f32_16x16x32_bf16(a[kt], bfr, acc, 0, 0, 0);
        }
#pragma unroll
        for (int q = 0; q < 4; ++q)
            out[(size_t)(m0 + kg * 4 + q) * 128 + nt * 16 + r] = f2b(acc[q]);
    }
}

// sup2 = h @ W2  (M=40000, K=128, N=64) — MFMA bf16, bf16 in.
__global__ __launch_bounds__(256) void gemm2_k(const ushort* __restrict__ h,
                                               const ushort* __restrict__ WT,
                                               ushort* __restrict__ out) {
    const int lane = threadIdx.x & 63;
    const int m0 = blockIdx.x * 64 + (threadIdx.x >> 6) * 16;
    const int r = lane & 15, kg = lane >> 4;

    bf16x8 a[4];
    const ushort* hp = h + (size_t)(m0 + r) * 128 + kg * 8;
#pragma unroll
    for (int kt = 0; kt < 4; ++kt) a[kt] = *(const bf16x8*)(hp + kt * 32);

#pragma unroll
    for (int nt = 0; nt < 4; ++nt) {
        const ushort* wp = WT + (size_t)(nt * 16 + r) * 128 + kg * 8;
        f32x4 acc = {0.f, 0.f, 0.f, 0.f};
#pragma unroll
        for (int kt = 0; kt < 4; ++kt) {
            const bf16x8 bfr = *(const bf16x8*)(wp + kt * 32);
            acc = __builtin_amdgcn_mfma_f32_16x16x32_bf16(a[kt], bfr, acc, 0, 0, 0);
        }
#pragma unroll
        for (int q = 0; q < 4; ++q)
            out[(size_t)(m0 + kg * 4 + q) * 64 + nt * 16 + r] = f2b(acc[q]);
    }
}

__global__ void hist_k(const int* __restrict__ edst, int* __restrict__ cnt) {
    int i = blockIdx.x * blockDim.x + threadIdx.x;
    if (i < N_EDGES) atomicAdd(&cnt[edst[i]], 1);
}

// ---- hierarchical scan: reduce per 1024-block -> scan 40 sums -> offset scan ----
__global__ __launch_bounds__(1024) void reduce_k(const int* __restrict__ cnt,
                                                 int* __restrict__ blksum) {
    __shared__ int ws[16];
    const int t = threadIdx.x;
    const int idx = blockIdx.x * 1024 + t;
    int v = (idx < N_NODES) ? cnt[idx] : 0;
#pragma unroll
    for (int d = 1; d < 64; d <<= 1) v += __shfl_xor(v, d);
    if ((t & 63) == 0) ws[t >> 6] = v;
    __syncthreads();
    if (t < 16) {
        int s = ws[t];
#pragma unroll
        for (int d = 1; d < 16; d <<= 1) s += __shfl_xor(s, d);
        if (t == 0) blksum[blockIdx.x] = s;
    }
}

__global__ void scanblk_k(int* __restrict__ blksum) {  // 1 block, 64 threads, inclusive
    const int t = threadIdx.x;
    int v = (t < NBLK) ? blksum[t] : 0;
#pragma unroll
    for (int d = 1; d < 64; d <<= 1) {
        int o = __shfl_up(v, d);
        if (t >= d) v += o;
    }
    if (t < NBLK) blksum[t] = v;
}

__global__ __launch_bounds__(1024) void scan3_k(const int* __restrict__ cnt,
                                                const int* __restrict__ blksum,
                                                int* __restrict__ row_ptr,
                                                int* __restrict__ cursor) {
    __shared__ int wsum[16];
    const int t = threadIdx.x, lane = t & 63, wv = t >> 6;
    const int idx = blockIdx.x * 1024 + t;
    const int v = (idx < N_NODES) ? cnt[idx] : 0;
    int incl = v;
#pragma unroll
    for (int d = 1; d < 64; d <<= 1) {
        int o = __shfl_up(incl, d);
        if (lane >= d) incl += o;
    }
    if (lane == 63) wsum[wv] = incl;
    __syncthreads();
    if (t < 16) {
        int s = wsum[t];
#pragma unroll
        for (int d = 1; d < 16; d <<= 1) {
            int o = __shfl_up(s, d);
            if (t >= d) s += o;
        }
        wsum[t] = s;
    }
    __syncthreads();
    const int base = (blockIdx.x ? blksum[blockIdx.x - 1] : 0) + (wv ? wsum[wv - 1] : 0);
    if (idx < N_NODES) {
        row_ptr[idx + 1] = base + incl;
        cursor[idx]      = base + incl - v;
    }
    if (idx == 0) row_ptr[0] = 0;
}

__global__ void scatter_k(const int* __restrict__ esrc, const int* __restrict__ edst,
                          const float* __restrict__ ew, int* __restrict__ cursor,
                          int* __restrict__ csrc, float* __restrict__ csrw) {
    int i = blockIdx.x * blockDim.x + threadIdx.x;
    if (i < N_EDGES) {
        int pos = atomicAdd(&cursor[edst[i]], 1);
        csrc[pos] = esrc[i];
        csrw[pos] = ew[i];
    }
}

// h = relu( spmm(adj, sup1) + b1 ),  D=128 bf16 in, bf16 out. One wave/node,
// lane covers features {2l, 2l+1}; 4-deep edge unroll -> 4 gathers in flight.
__global__ __launch_bounds__(256) void spmm1_k(const ushort* __restrict__ sup,
                                               const int* __restrict__ rp,
                                               const int* __restrict__ csrc,
                                               const float* __restrict__ csrw,
                                               const float* __restrict__ b,
                                               ushort* __restrict__ h) {
    const int wid = blockIdx.x * 4 + (threadIdx.x >> 6);
    const int lane = threadIdx.x & 63;
    const int e0 = rp[wid], e1 = rp[wid + 1];
    float a0 = 0.f, a1 = 0.f, a2 = 0.f, a3 = 0.f;
    int e = e0;
    for (; e + 4 <= e1; e += 4) {
        const int s0 = csrc[e], s1 = csrc[e + 1], s2 = csrc[e + 2], s3 = csrc[e + 3];
        const float w0 = csrw[e], w1 = csrw[e + 1], w2 = csrw[e + 2], w3 = csrw[e + 3];
        const uint v0 = ((const uint*)(sup + ((size_t)s0 << 7)))[lane];
        const uint v1 = ((const uint*)(sup + ((size_t)s1 << 7)))[lane];
        const uint v2 = ((const uint*)(sup + ((size_t)s2 << 7)))[lane];
        const uint v3 = ((const uint*)(sup + ((size_t)s3 << 7)))[lane];
        a0 = fmaf(w0, bl(v0), a0); a1 = fmaf(w0, bh(v0), a1);
        a2 = fmaf(w1, bl(v1), a2); a3 = fmaf(w1, bh(v1), a3);
        a0 = fmaf(w2, bl(v2), a0); a1 = fmaf(w2, bh(v2), a1);
        a2 = fmaf(w3, bl(v3), a2); a3 = fmaf(w3, bh(v3), a3);
    }
    for (; e < e1; ++e) {
        const int s = csrc[e];
        const float w = csrw[e];
        const uint v = ((const uint*)(sup + ((size_t)s << 7)))[lane];
        a0 = fmaf(w, bl(v), a0); a1 = fmaf(w, bh(v), a1);
    }
    a0 += a2; a1 += a3;
    const float2 bb = ((const float2*)b)[lane];
    a0 = fmaxf(a0 + bb.x, 0.f);
    a1 = fmaxf(a1 + bb.y, 0.f);
    ((uint*)h)[(size_t)wid * 64 + lane] = (uint)f2b(a0) | ((uint)f2b(a1) << 16);
}

// out = spmm(adj, sup2) + b2,  D=64 bf16 in, f32 out. One wave/node.
__global__ __launch_bounds__(256) void spmm2_k(const ushort* __restrict__ sup,
                                               const int* __restrict__ rp,
                                               const int* __restrict__ csrc,
                                               const float* __restrict__ csrw,
                                               const float* __restrict__ b,
                                               float* __restrict__ out) {
    const int wid = blockIdx.x * 4 + (threadIdx.x >> 6);
    const int lane = threadIdx.x & 63;
    const int e0 = rp[wid], e1 = rp[wid + 1];
    float a0 = 0.f, a1 = 0.f, a2 = 0.f, a3 = 0.f;
    int e = e0;
    for (; e + 4 <= e1; e += 4) {
        const int s0 = csrc[e], s1 = csrc[e + 1], s2 = csrc[e + 2], s3 = csrc[e + 3];
        const float w0 = csrw[e], w1 = csrw[e + 1], w2 = csrw[e + 2], w3 = csrw[e + 3];
        const float v0 = bfu(sup[((size_t)s0 << 6) + lane]);
        const float v1 = bfu(sup[((size_t)s1 << 6) + lane]);
        const float v2 = bfu(sup[((size_t)s2 << 6) + lane]);
        const float v3 = bfu(sup[((size_t)s3 << 6) + lane]);
        a0 = fmaf(w0, v0, a0);
        a1 = fmaf(w1, v1, a1);
        a2 = fmaf(w2, v2, a2);
        a3 = fmaf(w3, v3, a3);
    }
    for (; e < e1; ++e) {
        a0 = fmaf(csrw[e], bfu(sup[((size_t)csrc[e] << 6) + lane]), a0);
    }
    out[(size_t)wid * 64 + lane] = (a0 + a1) + (a2 + a3) + b[lane];
}

extern "C" void kernel_launch(void* const* d_in, const int* in_sizes, int n_in,
                              void* d_out, int out_size, void* d_ws, size_t ws_size,
                              hipStream_t stream) {
    const float* x    = (const float*)d_in[0];
    const int*   esrc = (const int*)d_in[1];
    const int*   edst = (const int*)d_in[2];
    const float* ew   = (const float*)d_in[3];
    const float* W1   = (const float*)d_in[4];
    const float* b1   = (const float*)d_in[5];
    const float* W2   = (const float*)d_in[6];
    const float* b2   = (const float*)d_in[7];
    float* out = (float*)d_out;

    char* ws = (char*)d_ws;
    ushort* sup1   = (ushort*)(ws + OFF_SUP1);
    ushort* h      = (ushort*)(ws + OFF_H);
    ushort* sup2   = (ushort*)(ws + OFF_SUP2);
    int*   row_ptr = (int*)(ws + OFF_ROWPTR);
    int*   cursor  = (int*)(ws + OFF_CURSOR);
    int*   cnt     = (int*)(ws + OFF_CNT);
    int*   blksum  = (int*)(ws + OFF_BLKSUM);
    int*   csrc    = (int*)(ws + OFF_CSRC);
    float* csrw    = (float*)(ws + OFF_CSRW);
    ushort* W1T    = (ushort*)(ws + OFF_W1T);
    ushort* W2T    = (ushort*)(ws + OFF_W2T);

    // CSR build
    hipMemsetAsync(cnt, 0, N_NODES * sizeof(int), stream);
    hist_k<<<(N_EDGES + 255) / 256, 256, 0, stream>>>(edst, cnt);
    reduce_k<<<NBLK, 1024, 0, stream>>>(cnt, blksum);
    scanblk_k<<<1, 64, 0, stream>>>(blksum);
    scan3_k<<<NBLK, 1024, 0, stream>>>(cnt, blksum, row_ptr, cursor);
    scatter_k<<<(N_EDGES + 255) / 256, 256, 0, stream>>>(esrc, edst, ew, cursor, csrc, csrw);

    // weights -> bf16 transposed
    wtrans_k<<<64, 256, 0, stream>>>(W1, W2, W1T, W2T);

    // layer 1
    gemm1_k<<<625, 256, 0, stream>>>(x, W1T, sup1);
    spmm1_k<<<10000, 256, 0, stream>>>(sup1, row_ptr, csrc, csrw, b1, h);

    // layer 2
    gemm2_k<<<625, 256, 0, stream>>>(h, W2T, sup2);
    spmm2_k<<<10000, 256, 0, stream>>>(sup2, row_ptr, csrc, csrw, b2, out);
}

// Round 4
// 167.672 us; speedup vs baseline: 2.0670x; 1.0085x over previous
//
#include <hip/hip_runtime.h>

#define N_NODES 40000
#define N_EDGES 640000
#define NFEAT   128
#define H1      128   // 2*NHID
#define H2      64    // NHID
#define NBLK    40    // ceil(40000/1024)

// ---- workspace layout (byte offsets, all 256-aligned) ----
#define OFF_SUP1   0UL          // 40000*128 bf16 = 10,240,000
#define OFF_H      10240000UL   // 40000*128 bf16 = 10,240,000
#define OFF_SUP2   20480000UL   // 40000*64  bf16 =  5,120,000
#define OFF_ROWPTR 25600000UL   // 40001 i32 -> 160,256 (padded)
#define OFF_CURSOR 25760256UL   // 40000 i32 -> 160,000
#define OFF_CNT    25920256UL   // 40000 i32 -> 160,000
#define OFF_BLKSUM 26080256UL   // 40 i32 -> 256
#define OFF_PREC   26080512UL   // 640000 u32 packed (src<<16 | bf16 w) -> 2,560,000
#define OFF_W1T    28640512UL   // 128*128 bf16 -> 32,768
#define OFF_W2T    28673280UL   // 64*128 bf16 -> 16,384
// total 28,689,664 bytes

typedef unsigned int uint;
typedef unsigned short ushort;
typedef __attribute__((ext_vector_type(8))) short bf16x8;
typedef __attribute__((ext_vector_type(4))) float f32x4;

// bf16 helpers (bit-level, round-to-nearest-even on pack)
__device__ __forceinline__ float bl(uint u) { union { uint i; float f; } c; c.i = u << 16; return c.f; }
__device__ __forceinline__ float bh(uint u) { union { uint i; float f; } c; c.i = u & 0xFFFF0000u; return c.f; }
__device__ __forceinline__ float bfu(ushort u) { union { uint i; float f; } c; c.i = ((uint)u) << 16; return c.f; }
__device__ __forceinline__ ushort f2b(float f) {
    union { float f; uint i; } c; c.f = f;
    uint u = c.i + 0x7FFFu + ((c.i >> 16) & 1u);
    return (ushort)(u >> 16);
}

// W1 [128][128] f32 -> W1T [n][k] bf16 ; W2 [128][64] f32 -> W2T [n][k] bf16
__global__ void wtrans_k(const float* __restrict__ W1, const float* __restrict__ W2,
                         ushort* __restrict__ W1T, ushort* __restrict__ W2T) {
    const int i = blockIdx.x * 256 + threadIdx.x;
    if (i < 128 * 128) {
        const int c = i >> 7, k = i & 127;
        W1T[i] = f2b(W1[k * 128 + c]);
    }
    if (i < 64 * 128) {
        const int c = i >> 7, k = i & 127;
        W2T[i] = f2b(W2[k * 64 + c]);
    }
}

// sup1 = x @ W1  (M=40000, K=128, N=128) — MFMA bf16, fp32-in cvt inline.
__global__ __launch_bounds__(256) void gemm1_k(const float* __restrict__ x,
                                               const ushort* __restrict__ WT,
                                               ushort* __restrict__ out) {
    const int lane = threadIdx.x & 63;
    const int m0 = blockIdx.x * 64 + (threadIdx.x >> 6) * 16;
    const int r = lane & 15, kg = lane >> 4;

    bf16x8 a[4];
    const float* xp = x + (size_t)(m0 + r) * 128 + kg * 8;
#pragma unroll
    for (int kt = 0; kt < 4; ++kt) {
        float xf[8];
        *(float4*)(xf)     = *(const float4*)(xp + kt * 32);
        *(float4*)(xf + 4) = *(const float4*)(xp + kt * 32 + 4);
        bf16x8 v;
#pragma unroll
        for (int i = 0; i < 8; ++i) v[i] = (short)f2b(xf[i]);
        a[kt] = v;
    }

#pragma unroll
    for (int nt = 0; nt < 8; ++nt) {
        const ushort* wp = WT + (size_t)(nt * 16 + r) * 128 + kg * 8;
        f32x4 acc = {0.f, 0.f, 0.f, 0.f};
#pragma unroll
        for (int kt = 0; kt < 4; ++kt) {
            const bf16x8 bfr = *(const bf16x8*)(wp + kt * 32);
            acc = __builtin_amdgcn_mfma_f32_16x16x32_bf16(a[kt], bfr, acc, 0, 0, 0);
        }
#pragma unroll
        for (int q = 0; q < 4; ++q)
            out[(size_t)(m0 + kg * 4 + q) * 128 + nt * 16 + r] = f2b(acc[q]);
    }
}

// sup2 = h @ W2  (M=40000, K=128, N=64) — MFMA bf16, bf16 in.
__global__ __launch_bounds__(256) void gemm2_k(const ushort* __restrict__ h,
                                               const ushort* __restrict__ WT,
                                               ushort* __restrict__ out) {
    const int lane = threadIdx.x & 63;
    const int m0 = blockIdx.x * 64 + (threadIdx.x >> 6) * 16;
    const int r = lane & 15, kg = lane >> 4;

    bf16x8 a[4];
    const ushort* hp = h + (size_t)(m0 + r) * 128 + kg * 8;
#pragma unroll
    for (int kt = 0; kt < 4; ++kt) a[kt] = *(const bf16x8*)(hp + kt * 32);

#pragma unroll
    for (int nt = 0; nt < 4; ++nt) {
        const ushort* wp = WT + (size_t)(nt * 16 + r) * 128 + kg * 8;
        f32x4 acc = {0.f, 0.f, 0.f, 0.f};
#pragma unroll
        for (int kt = 0; kt < 4; ++kt) {
            const bf16x8 bfr = *(const bf16x8*)(wp + kt * 32);
            acc = __builtin_amdgcn_mfma_f32_16x16x32_bf16(a[kt], bfr, acc, 0, 0, 0);
        }
#pragma unroll
        for (int q = 0; q < 4; ++q)
            out[(size_t)(m0 + kg * 4 + q) * 64 + nt * 16 + r] = f2b(acc[q]);
    }
}

__global__ void hist_k(const int* __restrict__ edst, int* __restrict__ cnt) {
    int i = blockIdx.x * blockDim.x + threadIdx.x;
    if (i < N_EDGES) atomicAdd(&cnt[edst[i]], 1);
}

// ---- hierarchical scan: reduce per 1024-block -> scan 40 sums -> offset scan ----
__global__ __launch_bounds__(1024) void reduce_k(const int* __restrict__ cnt,
                                                 int* __restrict__ blksum) {
    __shared__ int ws[16];
    const int t = threadIdx.x;
    const int idx = blockIdx.x * 1024 + t;
    int v = (idx < N_NODES) ? cnt[idx] : 0;
#pragma unroll
    for (int d = 1; d < 64; d <<= 1) v += __shfl_xor(v, d);
    if ((t & 63) == 0) ws[t >> 6] = v;
    __syncthreads();
    if (t < 16) {
        int s = ws[t];
#pragma unroll
        for (int d = 1; d < 16; d <<= 1) s += __shfl_xor(s, d);
        if (t == 0) blksum[blockIdx.x] = s;
    }
}

__global__ void scanblk_k(int* __restrict__ blksum) {  // 1 block, 64 threads, inclusive
    const int t = threadIdx.x;
    int v = (t < NBLK) ? blksum[t] : 0;
#pragma unroll
    for (int d = 1; d < 64; d <<= 1) {
        int o = __shfl_up(v, d);
        if (t >= d) v += o;
    }
    if (t < NBLK) blksum[t] = v;
}

__global__ __launch_bounds__(1024) void scan3_k(const int* __restrict__ cnt,
                                                const int* __restrict__ blksum,
                                                int* __restrict__ row_ptr,
                                                int* __restrict__ cursor) {
    __shared__ int wsum[16];
    const int t = threadIdx.x, lane = t & 63, wv = t >> 6;
    const int idx = blockIdx.x * 1024 + t;
    const int v = (idx < N_NODES) ? cnt[idx] : 0;
    int incl = v;
#pragma unroll
    for (int d = 1; d < 64; d <<= 1) {
        int o = __shfl_up(incl, d);
        if (lane >= d) incl += o;
    }
    if (lane == 63) wsum[wv] = incl;
    __syncthreads();
    if (t < 16) {
        int s = wsum[t];
#pragma unroll
        for (int d = 1; d < 16; d <<= 1) {
            int o = __shfl_up(s, d);
            if (t >= d) s += o;
        }
        wsum[t] = s;
    }
    __syncthreads();
    const int base = (blockIdx.x ? blksum[blockIdx.x - 1] : 0) + (wv ? wsum[wv - 1] : 0);
    if (idx < N_NODES) {
        row_ptr[idx + 1] = base + incl;
        cursor[idx]      = base + incl - v;
    }
    if (idx == 0) row_ptr[0] = 0;
}

// scatter packed record (src<<16 | bf16(w)) with NT store (write-through, no L2 bounce)
__global__ void scatter_k(const int* __restrict__ esrc, const int* __restrict__ edst,
                          const float* __restrict__ ew, int* __restrict__ cursor,
                          uint* __restrict__ prec) {
    int i = blockIdx.x * blockDim.x + threadIdx.x;
    if (i < N_EDGES) {
        const int pos = atomicAdd(&cursor[edst[i]], 1);
        const uint rec = ((uint)esrc[i] << 16) | (uint)f2b(ew[i]);
        __builtin_nontemporal_store(rec, &prec[pos]);
    }
}

// h = relu( spmm(adj, sup1) + b1 ),  D=128 bf16 in, bf16 out. One wave/node,
// lane covers features {2l, 2l+1}; 8-deep edge unroll -> 8 gathers in flight.
__global__ __launch_bounds__(256) void spmm1_k(const ushort* __restrict__ sup,
                                               const int* __restrict__ rp,
                                               const uint* __restrict__ prec,
                                               const float* __restrict__ b,
                                               ushort* __restrict__ h) {
    const int wid = blockIdx.x * 4 + (threadIdx.x >> 6);
    const int lane = threadIdx.x & 63;
    const int e0 = rp[wid], e1 = rp[wid + 1];
    const uint* sup32 = (const uint*)sup;
    float a0 = 0.f, a1 = 0.f, a2 = 0.f, a3 = 0.f;
    int e = e0;
    for (; e + 8 <= e1; e += 8) {
        uint r[8], v[8];
#pragma unroll
        for (int i = 0; i < 8; ++i) r[i] = prec[e + i];
#pragma unroll
        for (int i = 0; i < 8; ++i) v[i] = sup32[((size_t)(r[i] >> 16) << 6) + lane];
#pragma unroll
        for (int i = 0; i < 8; i += 2) {
            const float w0 = bl(r[i]), w1 = bl(r[i + 1]);
            a0 = fmaf(w0, bl(v[i]), a0);     a1 = fmaf(w0, bh(v[i]), a1);
            a2 = fmaf(w1, bl(v[i + 1]), a2); a3 = fmaf(w1, bh(v[i + 1]), a3);
        }
    }
    for (; e < e1; ++e) {
        const uint r0 = prec[e];
        const float w = bl(r0);
        const uint v = sup32[((size_t)(r0 >> 16) << 6) + lane];
        a0 = fmaf(w, bl(v), a0); a1 = fmaf(w, bh(v), a1);
    }
    a0 += a2; a1 += a3;
    const float2 bb = ((const float2*)b)[lane];
    a0 = fmaxf(a0 + bb.x, 0.f);
    a1 = fmaxf(a1 + bb.y, 0.f);
    ((uint*)h)[(size_t)wid * 64 + lane] = (uint)f2b(a0) | ((uint)f2b(a1) << 16);
}

// out = spmm(adj, sup2) + b2,  D=64 bf16 in, f32 out. One wave/node.
__global__ __launch_bounds__(256) void spmm2_k(const ushort* __restrict__ sup,
                                               const int* __restrict__ rp,
                                               const uint* __restrict__ prec,
                                               const float* __restrict__ b,
                                               float* __restrict__ out) {
    const int wid = blockIdx.x * 4 + (threadIdx.x >> 6);
    const int lane = threadIdx.x & 63;
    const int e0 = rp[wid], e1 = rp[wid + 1];
    float a0 = 0.f, a1 = 0.f, a2 = 0.f, a3 = 0.f;
    int e = e0;
    for (; e + 8 <= e1; e += 8) {
        uint r[8];
        float v[8];
#pragma unroll
        for (int i = 0; i < 8; ++i) r[i] = prec[e + i];
#pragma unroll
        for (int i = 0; i < 8; ++i) v[i] = bfu(sup[((size_t)(r[i] >> 16) << 6) + lane]);
        a0 = fmaf(bl(r[0]), v[0], a0);
        a1 = fmaf(bl(r[1]), v[1], a1);
        a2 = fmaf(bl(r[2]), v[2], a2);
        a3 = fmaf(bl(r[3]), v[3], a3);
        a0 = fmaf(bl(r[4]), v[4], a0);
        a1 = fmaf(bl(r[5]), v[5], a1);
        a2 = fmaf(bl(r[6]), v[6], a2);
        a3 = fmaf(bl(r[7]), v[7], a3);
    }
    for (; e < e1; ++e) {
        const uint r0 = prec[e];
        a0 = fmaf(bl(r0), bfu(sup[((size_t)(r0 >> 16) << 6) + lane]), a0);
    }
    const float res = (a0 + a1) + (a2 + a3) + b[lane];
    __builtin_nontemporal_store(res, &out[(size_t)wid * 64 + lane]);
}

extern "C" void kernel_launch(void* const* d_in, const int* in_sizes, int n_in,
                              void* d_out, int out_size, void* d_ws, size_t ws_size,
                              hipStream_t stream) {
    const float* x    = (const float*)d_in[0];
    const int*   esrc = (const int*)d_in[1];
    const int*   edst = (const int*)d_in[2];
    const float* ew   = (const float*)d_in[3];
    const float* W1   = (const float*)d_in[4];
    const float* b1   = (const float*)d_in[5];
    const float* W2   = (const float*)d_in[6];
    const float* b2   = (const float*)d_in[7];
    float* out = (float*)d_out;

    char* ws = (char*)d_ws;
    ushort* sup1   = (ushort*)(ws + OFF_SUP1);
    ushort* h      = (ushort*)(ws + OFF_H);
    ushort* sup2   = (ushort*)(ws + OFF_SUP2);
    int*   row_ptr = (int*)(ws + OFF_ROWPTR);
    int*   cursor  = (int*)(ws + OFF_CURSOR);
    int*   cnt     = (int*)(ws + OFF_CNT);
    int*   blksum  = (int*)(ws + OFF_BLKSUM);
    uint*  prec    = (uint*)(ws + OFF_PREC);
    ushort* W1T    = (ushort*)(ws + OFF_W1T);
    ushort* W2T    = (ushort*)(ws + OFF_W2T);

    // CSR build
    hipMemsetAsync(cnt, 0, N_NODES * sizeof(int), stream);
    hist_k<<<(N_EDGES + 255) / 256, 256, 0, stream>>>(edst, cnt);
    reduce_k<<<NBLK, 1024, 0, stream>>>(cnt, blksum);
    scanblk_k<<<1, 64, 0, stream>>>(blksum);
    scan3_k<<<NBLK, 1024, 0, stream>>>(cnt, blksum, row_ptr, cursor);
    scatter_k<<<(N_EDGES + 255) / 256, 256, 0, stream>>>(esrc, edst, ew, cursor, prec);

    // weights -> bf16 transposed
    wtrans_k<<<64, 256, 0, stream>>>(W1, W2, W1T, W2T);

    // layer 1
    gemm1_k<<<625, 256, 0, stream>>>(x, W1T, sup1);
    spmm1_k<<<10000, 256, 0, stream>>>(sup1, row_ptr, prec, b1, h);

    // layer 2
    gemm2_k<<<625, 256, 0, stream>>>(h, W2T, sup2);
    spmm2_k<<<10000, 256, 0, stream>>>(sup2, row_ptr, prec, b2, out);
}

// Round 5
// 150.198 us; speedup vs baseline: 2.3075x; 1.1163x over previous
//
#include <hip/hip_runtime.h>

#define N_NODES 40000
#define N_EDGES 640000
#define NFEAT   128
#define H1      128   // 2*NHID
#define H2      64    // NHID
#define NBLK    40    // ceil(40000/1024)

// ---- workspace layout (byte offsets, all 256-aligned) ----
#define OFF_SUP1   0UL          // 40000*128 bf16 = 10,240,000
#define OFF_H      10240000UL   // 40000*128 bf16 = 10,240,000
#define OFF_SUP2   20480000UL   // 40000*64  bf16 =  5,120,000
#define OFF_ROWPTR 25600000UL   // 40001 i32 -> 160,256 (padded)
#define OFF_RANK   25760256UL   // 640000 i32 -> 2,560,000
#define OFF_CNT    28320256UL   // 40000 i32 -> 160,000
#define OFF_BLKSUM 28480256UL   // 40 i32 -> 256
#define OFF_PREC   28480512UL   // 640000 u32 packed (src<<16 | bf16 w) -> 2,560,000
#define OFF_W1T    31040512UL   // 128*128 bf16 -> 32,768
#define OFF_W2T    31073280UL   // 64*128 bf16 -> 16,384
// total 31,089,664 bytes

typedef unsigned int uint;
typedef unsigned short ushort;
typedef __attribute__((ext_vector_type(8))) short bf16x8;
typedef __attribute__((ext_vector_type(4))) float f32x4;

// bf16 helpers (bit-level, round-to-nearest-even on pack)
__device__ __forceinline__ float bl(uint u) { union { uint i; float f; } c; c.i = u << 16; return c.f; }
__device__ __forceinline__ float bh(uint u) { union { uint i; float f; } c; c.i = u & 0xFFFF0000u; return c.f; }
__device__ __forceinline__ float bfu(ushort u) { union { uint i; float f; } c; c.i = ((uint)u) << 16; return c.f; }
__device__ __forceinline__ ushort f2b(float f) {
    union { float f; uint i; } c; c.f = f;
    uint u = c.i + 0x7FFFu + ((c.i >> 16) & 1u);
    return (ushort)(u >> 16);
}

__global__ void zero_k(int* __restrict__ cnt) {
    const int i = blockIdx.x * 256 + threadIdx.x;
    if (i < N_NODES) cnt[i] = 0;
}

// W1 [128][128] f32 -> W1T [n][k] bf16 ; W2 [128][64] f32 -> W2T [n][k] bf16
__global__ void wtrans_k(const float* __restrict__ W1, const float* __restrict__ W2,
                         ushort* __restrict__ W1T, ushort* __restrict__ W2T) {
    const int i = blockIdx.x * 256 + threadIdx.x;
    if (i < 128 * 128) {
        const int c = i >> 7, k = i & 127;
        W1T[i] = f2b(W1[k * 128 + c]);
    }
    if (i < 64 * 128) {
        const int c = i >> 7, k = i & 127;
        W2T[i] = f2b(W2[k * 64 + c]);
    }
}

// sup1 = x @ W1  (M=40000, K=128, N=128) — MFMA bf16, fp32-in cvt inline.
__global__ __launch_bounds__(256) void gemm1_k(const float* __restrict__ x,
                                               const ushort* __restrict__ WT,
                                               ushort* __restrict__ out) {
    const int lane = threadIdx.x & 63;
    const int m0 = blockIdx.x * 64 + (threadIdx.x >> 6) * 16;
    const int r = lane & 15, kg = lane >> 4;

    bf16x8 a[4];
    const float* xp = x + (size_t)(m0 + r) * 128 + kg * 8;
#pragma unroll
    for (int kt = 0; kt < 4; ++kt) {
        float xf[8];
        *(float4*)(xf)     = *(const float4*)(xp + kt * 32);
        *(float4*)(xf + 4) = *(const float4*)(xp + kt * 32 + 4);
        bf16x8 v;
#pragma unroll
        for (int i = 0; i < 8; ++i) v[i] = (short)f2b(xf[i]);
        a[kt] = v;
    }

#pragma unroll
    for (int nt = 0; nt < 8; ++nt) {
        const ushort* wp = WT + (size_t)(nt * 16 + r) * 128 + kg * 8;
        f32x4 acc = {0.f, 0.f, 0.f, 0.f};
#pragma unroll
        for (int kt = 0; kt < 4; ++kt) {
            const bf16x8 bfr = *(const bf16x8*)(wp + kt * 32);
            acc = __builtin_amdgcn_mfma_f32_16x16x32_bf16(a[kt], bfr, acc, 0, 0, 0);
        }
#pragma unroll
        for (int q = 0; q < 4; ++q)
            out[(size_t)(m0 + kg * 4 + q) * 128 + nt * 16 + r] = f2b(acc[q]);
    }
}

// sup2 = h @ W2  (M=40000, K=128, N=64) — MFMA bf16, bf16 in.
__global__ __launch_bounds__(256) void gemm2_k(const ushort* __restrict__ h,
                                               const ushort* __restrict__ WT,
                                               ushort* __restrict__ out) {
    const int lane = threadIdx.x & 63;
    const int m0 = blockIdx.x * 64 + (threadIdx.x >> 6) * 16;
    const int r = lane & 15, kg = lane >> 4;

    bf16x8 a[4];
    const ushort* hp = h + (size_t)(m0 + r) * 128 + kg * 8;
#pragma unroll
    for (int kt = 0; kt < 4; ++kt) a[kt] = *(const bf16x8*)(hp + kt * 32);

#pragma unroll
    for (int nt = 0; nt < 4; ++nt) {
        const ushort* wp = WT + (size_t)(nt * 16 + r) * 128 + kg * 8;
        f32x4 acc = {0.f, 0.f, 0.f, 0.f};
#pragma unroll
        for (int kt = 0; kt < 4; ++kt) {
            const bf16x8 bfr = *(const bf16x8*)(wp + kt * 32);
            acc = __builtin_amdgcn_mfma_f32_16x16x32_bf16(a[kt], bfr, acc, 0, 0, 0);
        }
#pragma unroll
        for (int q = 0; q < 4; ++q)
            out[(size_t)(m0 + kg * 4 + q) * 64 + nt * 16 + r] = f2b(acc[q]);
    }
}

// histogram + per-edge rank within its dst (coalesced rank write)
__global__ void hist_k(const int* __restrict__ edst, int* __restrict__ cnt,
                       int* __restrict__ rank) {
    int i = blockIdx.x * blockDim.x + threadIdx.x;
    if (i < N_EDGES) rank[i] = atomicAdd(&cnt[edst[i]], 1);
}

// ---- hierarchical scan: reduce per 1024-block -> scan 40 sums -> offset scan ----
__global__ __launch_bounds__(1024) void reduce_k(const int* __restrict__ cnt,
                                                 int* __restrict__ blksum) {
    __shared__ int ws[16];
    const int t = threadIdx.x;
    const int idx = blockIdx.x * 1024 + t;
    int v = (idx < N_NODES) ? cnt[idx] : 0;
#pragma unroll
    for (int d = 1; d < 64; d <<= 1) v += __shfl_xor(v, d);
    if ((t & 63) == 0) ws[t >> 6] = v;
    __syncthreads();
    if (t < 16) {
        int s = ws[t];
#pragma unroll
        for (int d = 1; d < 16; d <<= 1) s += __shfl_xor(s, d);
        if (t == 0) blksum[blockIdx.x] = s;
    }
}

__global__ void scanblk_k(int* __restrict__ blksum) {  // 1 block, 64 threads, inclusive
    const int t = threadIdx.x;
    int v = (t < NBLK) ? blksum[t] : 0;
#pragma unroll
    for (int d = 1; d < 64; d <<= 1) {
        int o = __shfl_up(v, d);
        if (t >= d) v += o;
    }
    if (t < NBLK) blksum[t] = v;
}

__global__ __launch_bounds__(1024) void scan3_k(const int* __restrict__ cnt,
                                                const int* __restrict__ blksum,
                                                int* __restrict__ row_ptr) {
    __shared__ int wsum[16];
    const int t = threadIdx.x, lane = t & 63, wv = t >> 6;
    const int idx = blockIdx.x * 1024 + t;
    const int v = (idx < N_NODES) ? cnt[idx] : 0;
    int incl = v;
#pragma unroll
    for (int d = 1; d < 64; d <<= 1) {
        int o = __shfl_up(incl, d);
        if (lane >= d) incl += o;
    }
    if (lane == 63) wsum[wv] = incl;
    __syncthreads();
    if (t < 16) {
        int s = wsum[t];
#pragma unroll
        for (int d = 1; d < 16; d <<= 1) {
            int o = __shfl_up(s, d);
            if (t >= d) s += o;
        }
        wsum[t] = s;
    }
    __syncthreads();
    const int base = (blockIdx.x ? blksum[blockIdx.x - 1] : 0) + (wv ? wsum[wv - 1] : 0);
    if (idx < N_NODES) row_ptr[idx + 1] = base + incl;
    if (idx == 0) row_ptr[0] = 0;
}

// scatter packed record (src<<16 | bf16(w)); pos = row_ptr[dst] + rank — no atomic.
__global__ void scatter_k(const int* __restrict__ esrc, const int* __restrict__ edst,
                          const float* __restrict__ ew, const int* __restrict__ rp,
                          const int* __restrict__ rank, uint* __restrict__ prec) {
    int i = blockIdx.x * blockDim.x + threadIdx.x;
    if (i < N_EDGES) {
        const int pos = rp[edst[i]] + rank[i];
        const uint rec = ((uint)esrc[i] << 16) | (uint)f2b(ew[i]);
        __builtin_nontemporal_store(rec, &prec[pos]);
    }
}

// h = relu( spmm(adj, sup1) + b1 ),  D=128 bf16 in, bf16 out. One wave/node,
// lane covers features {2l, 2l+1}; 8-deep edge unroll -> 8 gathers in flight.
__global__ __launch_bounds__(256) void spmm1_k(const ushort* __restrict__ sup,
                                               const int* __restrict__ rp,
                                               const uint* __restrict__ prec,
                                               const float* __restrict__ b,
                                               ushort* __restrict__ h) {
    const int wid = blockIdx.x * 4 + (threadIdx.x >> 6);
    const int lane = threadIdx.x & 63;
    const int e0 = rp[wid], e1 = rp[wid + 1];
    const uint* sup32 = (const uint*)sup;
    float a0 = 0.f, a1 = 0.f, a2 = 0.f, a3 = 0.f;
    int e = e0;
    for (; e + 8 <= e1; e += 8) {
        uint r[8], v[8];
#pragma unroll
        for (int i = 0; i < 8; ++i) r[i] = prec[e + i];
#pragma unroll
        for (int i = 0; i < 8; ++i) v[i] = sup32[((size_t)(r[i] >> 16) << 6) + lane];
#pragma unroll
        for (int i = 0; i < 8; i += 2) {
            const float w0 = bl(r[i]), w1 = bl(r[i + 1]);
            a0 = fmaf(w0, bl(v[i]), a0);     a1 = fmaf(w0, bh(v[i]), a1);
            a2 = fmaf(w1, bl(v[i + 1]), a2); a3 = fmaf(w1, bh(v[i + 1]), a3);
        }
    }
    for (; e < e1; ++e) {
        const uint r0 = prec[e];
        const float w = bl(r0);
        const uint v = sup32[((size_t)(r0 >> 16) << 6) + lane];
        a0 = fmaf(w, bl(v), a0); a1 = fmaf(w, bh(v), a1);
    }
    a0 += a2; a1 += a3;
    const float2 bb = ((const float2*)b)[lane];
    a0 = fmaxf(a0 + bb.x, 0.f);
    a1 = fmaxf(a1 + bb.y, 0.f);
    ((uint*)h)[(size_t)wid * 64 + lane] = (uint)f2b(a0) | ((uint)f2b(a1) << 16);
}

// out = spmm(adj, sup2) + b2,  D=64 bf16 in, f32 out. One wave/node.
__global__ __launch_bounds__(256) void spmm2_k(const ushort* __restrict__ sup,
                                               const int* __restrict__ rp,
                                               const uint* __restrict__ prec,
                                               const float* __restrict__ b,
                                               float* __restrict__ out) {
    const int wid = blockIdx.x * 4 + (threadIdx.x >> 6);
    const int lane = threadIdx.x & 63;
    const int e0 = rp[wid], e1 = rp[wid + 1];
    float a0 = 0.f, a1 = 0.f, a2 = 0.f, a3 = 0.f;
    int e = e0;
    for (; e + 8 <= e1; e += 8) {
        uint r[8];
        float v[8];
#pragma unroll
        for (int i = 0; i < 8; ++i) r[i] = prec[e + i];
#pragma unroll
        for (int i = 0; i < 8; ++i) v[i] = bfu(sup[((size_t)(r[i] >> 16) << 6) + lane]);
        a0 = fmaf(bl(r[0]), v[0], a0);
        a1 = fmaf(bl(r[1]), v[1], a1);
        a2 = fmaf(bl(r[2]), v[2], a2);
        a3 = fmaf(bl(r[3]), v[3], a3);
        a0 = fmaf(bl(r[4]), v[4], a0);
        a1 = fmaf(bl(r[5]), v[5], a1);
        a2 = fmaf(bl(r[6]), v[6], a2);
        a3 = fmaf(bl(r[7]), v[7], a3);
    }
    for (; e < e1; ++e) {
        const uint r0 = prec[e];
        a0 = fmaf(bl(r0), bfu(sup[((size_t)(r0 >> 16) << 6) + lane]), a0);
    }
    const float res = (a0 + a1) + (a2 + a3) + b[lane];
    __builtin_nontemporal_store(res, &out[(size_t)wid * 64 + lane]);
}

extern "C" void kernel_launch(void* const* d_in, const int* in_sizes, int n_in,
                              void* d_out, int out_size, void* d_ws, size_t ws_size,
                              hipStream_t stream) {
    const float* x    = (const float*)d_in[0];
    const int*   esrc = (const int*)d_in[1];
    const int*   edst = (const int*)d_in[2];
    const float* ew   = (const float*)d_in[3];
    const float* W1   = (const float*)d_in[4];
    const float* b1   = (const float*)d_in[5];
    const float* W2   = (const float*)d_in[6];
    const float* b2   = (const float*)d_in[7];
    float* out = (float*)d_out;

    char* ws = (char*)d_ws;
    ushort* sup1   = (ushort*)(ws + OFF_SUP1);
    ushort* h      = (ushort*)(ws + OFF_H);
    ushort* sup2   = (ushort*)(ws + OFF_SUP2);
    int*   row_ptr = (int*)(ws + OFF_ROWPTR);
    int*   rank    = (int*)(ws + OFF_RANK);
    int*   cnt     = (int*)(ws + OFF_CNT);
    int*   blksum  = (int*)(ws + OFF_BLKSUM);
    uint*  prec    = (uint*)(ws + OFF_PREC);
    ushort* W1T    = (ushort*)(ws + OFF_W1T);
    ushort* W2T    = (ushort*)(ws + OFF_W2T);

    // CSR build
    zero_k<<<(N_NODES + 255) / 256, 256, 0, stream>>>(cnt);
    hist_k<<<(N_EDGES + 255) / 256, 256, 0, stream>>>(edst, cnt, rank);
    reduce_k<<<NBLK, 1024, 0, stream>>>(cnt, blksum);
    scanblk_k<<<1, 64, 0, stream>>>(blksum);
    scan3_k<<<NBLK, 1024, 0, stream>>>(cnt, blksum, row_ptr);
    scatter_k<<<(N_EDGES + 255) / 256, 256, 0, stream>>>(esrc, edst, ew, row_ptr, rank, prec);

    // weights -> bf16 transposed
    wtrans_k<<<64, 256, 0, stream>>>(W1, W2, W1T, W2T);

    // layer 1
    gemm1_k<<<625, 256, 0, stream>>>(x, W1T, sup1);
    spmm1_k<<<10000, 256, 0, stream>>>(sup1, row_ptr, prec, b1, h);

    // layer 2
    gemm2_k<<<625, 256, 0, stream>>>(h, W2T, sup2);
    spmm2_k<<<10000, 256, 0, stream>>>(sup2, row_ptr, prec, b2, out);
}

// Round 6
// 136.292 us; speedup vs baseline: 2.5430x; 1.1020x over previous
//
#include <hip/hip_runtime.h>

#define N_NODES 40000
#define N_EDGES 640000
#define NFEAT   128
#define H1      128   // 2*NHID
#define H2      64    // NHID
#define NBLK    40    // ceil(40000/1024)

// ---- workspace layout (byte offsets, all 256-aligned) ----
#define OFF_SUP1   0UL          // 40000*128 bf16 = 10,240,000
#define OFF_H      10240000UL   // 40000*128 bf16 = 10,240,000
#define OFF_SUP2   20480000UL   // 40000*64  bf16 =  5,120,000
#define OFF_ROWPTR 25600000UL   // 40001 i32 -> 160,256 (padded)
#define OFF_RANK   25760256UL   // 640000 i32 -> 2,560,000
#define OFF_CNT    28320256UL   // 40000 i32 -> 160,000
#define OFF_BLKSUM 28480256UL   // 40 i32 -> 256
#define OFF_PREC   28480512UL   // 640000 u32 packed (src<<16 | bf16 w) -> 2,560,000
#define OFF_W1T    31040512UL   // 128*128 bf16 -> 32,768
#define OFF_W2T    31073280UL   // 64*128 bf16 -> 16,384
// total 31,089,664 bytes

typedef unsigned int uint;
typedef unsigned short ushort;
typedef __attribute__((ext_vector_type(8))) short bf16x8;
typedef __attribute__((ext_vector_type(4))) float f32x4;
typedef __attribute__((ext_vector_type(2))) float f32x2;

// bf16 helpers (bit-level, round-to-nearest-even on pack)
__device__ __forceinline__ float bl(uint u) { union { uint i; float f; } c; c.i = u << 16; return c.f; }
__device__ __forceinline__ float bh(uint u) { union { uint i; float f; } c; c.i = u & 0xFFFF0000u; return c.f; }
__device__ __forceinline__ ushort f2b(float f) {
    union { float f; uint i; } c; c.f = f;
    uint u = c.i + 0x7FFFu + ((c.i >> 16) & 1u);
    return (ushort)(u >> 16);
}

// zero cnt + W1 [128][128] f32 -> W1T [n][k] bf16 ; W2 [128][64] f32 -> W2T [n][k] bf16
__global__ void init_k(int* __restrict__ cnt,
                       const float* __restrict__ W1, const float* __restrict__ W2,
                       ushort* __restrict__ W1T, ushort* __restrict__ W2T) {
    const int i = blockIdx.x * 256 + threadIdx.x;
    if (i < N_NODES) cnt[i] = 0;
    if (i < 128 * 128) {
        const int c = i >> 7, k = i & 127;
        W1T[i] = f2b(W1[k * 128 + c]);
    }
    if (i < 64 * 128) {
        const int c = i >> 7, k = i & 127;
        W2T[i] = f2b(W2[k * 64 + c]);
    }
}

// histogram + per-edge rank within its dst (coalesced rank write)
__global__ void hist_k(const int* __restrict__ edst, int* __restrict__ cnt,
                       int* __restrict__ rank) {
    int i = blockIdx.x * blockDim.x + threadIdx.x;
    if (i < N_EDGES) rank[i] = atomicAdd(&cnt[edst[i]], 1);
}

// per-1024-block sums
__global__ __launch_bounds__(1024) void reduce_k(const int* __restrict__ cnt,
                                                 int* __restrict__ blksum) {
    __shared__ int ws[16];
    const int t = threadIdx.x;
    const int idx = blockIdx.x * 1024 + t;
    int v = (idx < N_NODES) ? cnt[idx] : 0;
#pragma unroll
    for (int d = 1; d < 64; d <<= 1) v += __shfl_xor(v, d);
    if ((t & 63) == 0) ws[t >> 6] = v;
    __syncthreads();
    if (t < 16) {
        int s = ws[t];
#pragma unroll
        for (int d = 1; d < 16; d <<= 1) s += __shfl_xor(s, d);
        if (t == 0) blksum[blockIdx.x] = s;
    }
}

// full scan: each block inline-scans the 40 block sums (wave 0) + local scan
__global__ __launch_bounds__(1024) void scan3_k(const int* __restrict__ cnt,
                                                const int* __restrict__ blksum,
                                                int* __restrict__ row_ptr) {
    __shared__ int wsum[16];
    __shared__ int bpref;
    const int t = threadIdx.x, lane = t & 63, wv = t >> 6;
    const int idx = blockIdx.x * 1024 + t;
    const int v = (idx < N_NODES) ? cnt[idx] : 0;
    int incl = v;
#pragma unroll
    for (int d = 1; d < 64; d <<= 1) {
        int o = __shfl_up(incl, d);
        if (lane >= d) incl += o;
    }
    if (lane == 63) wsum[wv] = incl;
    if (t < 64) {  // wave 0: inclusive scan of the 40 block sums
        int s = (t < NBLK) ? blksum[t] : 0;
#pragma unroll
        for (int d = 1; d < 64; d <<= 1) {
            int o = __shfl_up(s, d);
            if (t >= d) s += o;
        }
        if (blockIdx.x == 0) { if (t == 0) bpref = 0; }
        else if (t == blockIdx.x - 1) bpref = s;
    }
    __syncthreads();
    if (t < 16) {
        int s = wsum[t];
#pragma unroll
        for (int d = 1; d < 16; d <<= 1) {
            int o = __shfl_up(s, d);
            if (t >= d) s += o;
        }
        wsum[t] = s;
    }
    __syncthreads();
    const int base = bpref + (wv ? wsum[wv - 1] : 0);
    if (idx < N_NODES) row_ptr[idx + 1] = base + incl;
    if (idx == 0) row_ptr[0] = 0;
}

// fused: blocks [0,2500) scatter packed records; blocks [2500,3125) gemm1 (MFMA).
__global__ __launch_bounds__(256) void scatgemm1_k(const int* __restrict__ esrc,
                                                   const int* __restrict__ edst,
                                                   const float* __restrict__ ew,
                                                   const int* __restrict__ rp,
                                                   const int* __restrict__ rank,
                                                   uint* __restrict__ prec,
                                                   const float* __restrict__ x,
                                                   const ushort* __restrict__ WT,
                                                   ushort* __restrict__ outS) {
    if (blockIdx.x < 2500) {
        const int i = blockIdx.x * 256 + threadIdx.x;  // 2500*256 == N_EDGES exactly
        const int pos = rp[edst[i]] + rank[i];
        const uint rec = ((uint)esrc[i] << 16) | (uint)f2b(ew[i]);
        __builtin_nontemporal_store(rec, &prec[pos]);
        return;
    }
    // gemm1: sup1 = x @ W1 (M=40000, K=128, N=128), fp32->bf16 cvt inline
    const int bid = blockIdx.x - 2500;
    const int lane = threadIdx.x & 63;
    const int m0 = bid * 64 + (threadIdx.x >> 6) * 16;
    const int r = lane & 15, kg = lane >> 4;

    bf16x8 a[4];
    const float* xp = x + (size_t)(m0 + r) * 128 + kg * 8;
#pragma unroll
    for (int kt = 0; kt < 4; ++kt) {
        float xf[8];
        *(float4*)(xf)     = *(const float4*)(xp + kt * 32);
        *(float4*)(xf + 4) = *(const float4*)(xp + kt * 32 + 4);
        bf16x8 v;
#pragma unroll
        for (int i = 0; i < 8; ++i) v[i] = (short)f2b(xf[i]);
        a[kt] = v;
    }

#pragma unroll
    for (int nt = 0; nt < 8; ++nt) {
        const ushort* wp = WT + (size_t)(nt * 16 + r) * 128 + kg * 8;
        f32x4 acc = {0.f, 0.f, 0.f, 0.f};
#pragma unroll
        for (int kt = 0; kt < 4; ++kt) {
            const bf16x8 bfr = *(const bf16x8*)(wp + kt * 32);
            acc = __builtin_amdgcn_mfma_f32_16x16x32_bf16(a[kt], bfr, acc, 0, 0, 0);
        }
#pragma unroll
        for (int q = 0; q < 4; ++q)
            outS[(size_t)(m0 + kg * 4 + q) * 128 + nt * 16 + r] = f2b(acc[q]);
    }
}

// sup2 = h @ W2  (M=40000, K=128, N=64) — MFMA bf16, bf16 in.
__global__ __launch_bounds__(256) void gemm2_k(const ushort* __restrict__ h,
                                               const ushort* __restrict__ WT,
                                               ushort* __restrict__ out) {
    const int lane = threadIdx.x & 63;
    const int m0 = blockIdx.x * 64 + (threadIdx.x >> 6) * 16;
    const int r = lane & 15, kg = lane >> 4;

    bf16x8 a[4];
    const ushort* hp = h + (size_t)(m0 + r) * 128 + kg * 8;
#pragma unroll
    for (int kt = 0; kt < 4; ++kt) a[kt] = *(const bf16x8*)(hp + kt * 32);

#pragma unroll
    for (int nt = 0; nt < 4; ++nt) {
        const ushort* wp = WT + (size_t)(nt * 16 + r) * 128 + kg * 8;
        f32x4 acc = {0.f, 0.f, 0.f, 0.f};
#pragma unroll
        for (int kt = 0; kt < 4; ++kt) {
            const bf16x8 bfr = *(const bf16x8*)(wp + kt * 32);
            acc = __builtin_amdgcn_mfma_f32_16x16x32_bf16(a[kt], bfr, acc, 0, 0, 0);
        }
#pragma unroll
        for (int q = 0; q < 4; ++q)
            out[(size_t)(m0 + kg * 4 + q) * 64 + nt * 16 + r] = f2b(acc[q]);
    }
}

// h = relu( spmm(adj, sup1) + b1 ).  Wave per node; lanes 0-31 take even edges,
// lanes 32-63 odd edges; each lane gathers 8B (feats 4*l32..+3). 4 gathers in flight.
__global__ __launch_bounds__(256) void spmm1_k(const ushort* __restrict__ sup,
                                               const int* __restrict__ rp,
                                               const uint* __restrict__ prec,
                                               const float* __restrict__ b,
                                               ushort* __restrict__ h) {
    const int wid = blockIdx.x * 4 + (threadIdx.x >> 6);
    const int lane = threadIdx.x & 63;
    const int half = lane >> 5, l32 = lane & 31;
    const int e0 = rp[wid], e1 = rp[wid + 1];
    const uint2* sup64 = (const uint2*)sup;
    float c0 = 0.f, c1 = 0.f, c2 = 0.f, c3 = 0.f, c4 = 0.f, c5 = 0.f, c6 = 0.f, c7 = 0.f;
    int e = e0;
    for (; e + 8 <= e1; e += 8) {
        const uint r0 = prec[e + half],     r1 = prec[e + 2 + half];
        const uint r2 = prec[e + 4 + half], r3 = prec[e + 6 + half];
        const uint2 v0 = sup64[((size_t)(r0 >> 16) << 5) + l32];
        const uint2 v1 = sup64[((size_t)(r1 >> 16) << 5) + l32];
        const uint2 v2 = sup64[((size_t)(r2 >> 16) << 5) + l32];
        const uint2 v3 = sup64[((size_t)(r3 >> 16) << 5) + l32];
        const float w0 = bl(r0), w1 = bl(r1), w2 = bl(r2), w3 = bl(r3);
        c0 = fmaf(w0, bl(v0.x), c0); c1 = fmaf(w0, bh(v0.x), c1);
        c2 = fmaf(w0, bl(v0.y), c2); c3 = fmaf(w0, bh(v0.y), c3);
        c4 = fmaf(w1, bl(v1.x), c4); c5 = fmaf(w1, bh(v1.x), c5);
        c6 = fmaf(w1, bl(v1.y), c6); c7 = fmaf(w1, bh(v1.y), c7);
        c0 = fmaf(w2, bl(v2.x), c0); c1 = fmaf(w2, bh(v2.x), c1);
        c2 = fmaf(w2, bl(v2.y), c2); c3 = fmaf(w2, bh(v2.y), c3);
        c4 = fmaf(w3, bl(v3.x), c4); c5 = fmaf(w3, bh(v3.x), c5);
        c6 = fmaf(w3, bl(v3.y), c6); c7 = fmaf(w3, bh(v3.y), c7);
    }
    for (; e + 2 <= e1; e += 2) {
        const uint r0 = prec[e + half];
        const uint2 v0 = sup64[((size_t)(r0 >> 16) << 5) + l32];
        const float w0 = bl(r0);
        c0 = fmaf(w0, bl(v0.x), c0); c1 = fmaf(w0, bh(v0.x), c1);
        c2 = fmaf(w0, bl(v0.y), c2); c3 = fmaf(w0, bh(v0.y), c3);
    }
    if (e < e1 && half == 0) {
        const uint r0 = prec[e];
        const uint2 v0 = sup64[((size_t)(r0 >> 16) << 5) + l32];
        const float w0 = bl(r0);
        c0 = fmaf(w0, bl(v0.x), c0); c1 = fmaf(w0, bh(v0.x), c1);
        c2 = fmaf(w0, bl(v0.y), c2); c3 = fmaf(w0, bh(v0.y), c3);
    }
    float f0 = c0 + c4, f1 = c1 + c5, f2 = c2 + c6, f3 = c3 + c7;
    f0 += __shfl_xor(f0, 32); f1 += __shfl_xor(f1, 32);
    f2 += __shfl_xor(f2, 32); f3 += __shfl_xor(f3, 32);
    if (half == 0) {
        const float4 bb = ((const float4*)b)[l32];
        f0 = fmaxf(f0 + bb.x, 0.f);
        f1 = fmaxf(f1 + bb.y, 0.f);
        f2 = fmaxf(f2 + bb.z, 0.f);
        f3 = fmaxf(f3 + bb.w, 0.f);
        uint2 pk;
        pk.x = (uint)f2b(f0) | ((uint)f2b(f1) << 16);
        pk.y = (uint)f2b(f2) | ((uint)f2b(f3) << 16);
        ((uint2*)h)[(size_t)wid * 32 + l32] = pk;
    }
}

// out = spmm(adj, sup2) + b2.  Wave per node; half-wave per edge, 4B/lane gathers.
__global__ __launch_bounds__(256) void spmm2_k(const ushort* __restrict__ sup,
                                               const int* __restrict__ rp,
                                               const uint* __restrict__ prec,
                                               const float* __restrict__ b,
                                               float* __restrict__ out) {
    const int wid = blockIdx.x * 4 + (threadIdx.x >> 6);
    const int lane = threadIdx.x & 63;
    const int half = lane >> 5, l32 = lane & 31;
    const int e0 = rp[wid], e1 = rp[wid + 1];
    const uint* sup32 = (const uint*)sup;
    float d0 = 0.f, d1 = 0.f, d2 = 0.f, d3 = 0.f;
    int e = e0;
    for (; e + 8 <= e1; e += 8) {
        const uint r0 = prec[e + half],     r1 = prec[e + 2 + half];
        const uint r2 = prec[e + 4 + half], r3 = prec[e + 6 + half];
        const uint v0 = sup32[((size_t)(r0 >> 16) << 5) + l32];
        const uint v1 = sup32[((size_t)(r1 >> 16) << 5) + l32];
        const uint v2 = sup32[((size_t)(r2 >> 16) << 5) + l32];
        const uint v3 = sup32[((size_t)(r3 >> 16) << 5) + l32];
        d0 = fmaf(bl(r0), bl(v0), d0); d1 = fmaf(bl(r0), bh(v0), d1);
        d2 = fmaf(bl(r1), bl(v1), d2); d3 = fmaf(bl(r1), bh(v1), d3);
        d0 = fmaf(bl(r2), bl(v2), d0); d1 = fmaf(bl(r2), bh(v2), d1);
        d2 = fmaf(bl(r3), bl(v3), d2); d3 = fmaf(bl(r3), bh(v3), d3);
    }
    for (; e + 2 <= e1; e += 2) {
        const uint r0 = prec[e + half];
        const uint v0 = sup32[((size_t)(r0 >> 16) << 5) + l32];
        d0 = fmaf(bl(r0), bl(v0), d0); d1 = fmaf(bl(r0), bh(v0), d1);
    }
    if (e < e1 && half == 0) {
        const uint r0 = prec[e];
        const uint v0 = sup32[((size_t)(r0 >> 16) << 5) + l32];
        d0 = fmaf(bl(r0), bl(v0), d0); d1 = fmaf(bl(r0), bh(v0), d1);
    }
    float g0 = d0 + d2, g1 = d1 + d3;
    g0 += __shfl_xor(g0, 32); g1 += __shfl_xor(g1, 32);
    if (half == 0) {
        const float2 bb = ((const float2*)b)[l32];
        f32x2 res = {g0 + bb.x, g1 + bb.y};
        __builtin_nontemporal_store(res, (f32x2*)out + (size_t)wid * 32 + l32);
    }
}

extern "C" void kernel_launch(void* const* d_in, const int* in_sizes, int n_in,
                              void* d_out, int out_size, void* d_ws, size_t ws_size,
                              hipStream_t stream) {
    const float* x    = (const float*)d_in[0];
    const int*   esrc = (const int*)d_in[1];
    const int*   edst = (const int*)d_in[2];
    const float* ew   = (const float*)d_in[3];
    const float* W1   = (const float*)d_in[4];
    const float* b1   = (const float*)d_in[5];
    const float* W2   = (const float*)d_in[6];
    const float* b2   = (const float*)d_in[7];
    float* out = (float*)d_out;

    char* ws = (char*)d_ws;
    ushort* sup1   = (ushort*)(ws + OFF_SUP1);
    ushort* h      = (ushort*)(ws + OFF_H);
    ushort* sup2   = (ushort*)(ws + OFF_SUP2);
    int*   row_ptr = (int*)(ws + OFF_ROWPTR);
    int*   rank    = (int*)(ws + OFF_RANK);
    int*   cnt     = (int*)(ws + OFF_CNT);
    int*   blksum  = (int*)(ws + OFF_BLKSUM);
    uint*  prec    = (uint*)(ws + OFF_PREC);
    ushort* W1T    = (ushort*)(ws + OFF_W1T);
    ushort* W2T    = (ushort*)(ws + OFF_W2T);

    // CSR build + weight prep
    init_k<<<157, 256, 0, stream>>>(cnt, W1, W2, W1T, W2T);
    hist_k<<<2500, 256, 0, stream>>>(edst, cnt, rank);
    reduce_k<<<NBLK, 1024, 0, stream>>>(cnt, blksum);
    scan3_k<<<NBLK, 1024, 0, stream>>>(cnt, blksum, row_ptr);
    scatgemm1_k<<<3125, 256, 0, stream>>>(esrc, edst, ew, row_ptr, rank, prec, x, W1T, sup1);

    // layer 1 aggregate
    spmm1_k<<<10000, 256, 0, stream>>>(sup1, row_ptr, prec, b1, h);

    // layer 2
    gemm2_k<<<625, 256, 0, stream>>>(h, W2T, sup2);
    spmm2_k<<<10000, 256, 0, stream>>>(sup2, row_ptr, prec, b2, out);
}